// Round 6
// baseline (49.783 us; speedup 1.0000x reference)
//
#include <hip/hip_runtime.h>

#define HALO 5
#define TILE_W 32
#define TILE_H 16
#define SM_R 26        // halo rows per 32x16 tile
#define SM_C 42        // halo cols
#define PSTR 43        // plane stride in float4: 172 floats == 12 mod 32 banks (rotation 3)
#define BATCH 16
#define CH 3
#define H 512
#define W 512
#define HW (H*W)
#define NBLOCKS 8192   // 16 batch x 32 row-strips x 16 col-strips

__global__ __launch_bounds__(256, 8) void ssim_tile_kernel(
    const float* __restrict__ pred, const float* __restrict__ gt,
    float* __restrict__ partial)
{
    // ONE float4 plane, two lives (aliased across a barrier):
    //  Phase A: per-pixel channel-reduced (sum_p, sum_g, sum_pp+gg, sum_pg),
    //           [r=0..25][sc=0..41]
    //  Phase B: horizontal box sums, NON-transposed [y=0..25][x=0..31]
    //           (fits inside phase-A footprint; stage-3 reads are row-broadcast)
    __shared__ float4 plane[SM_R][PSTR];   // 17.9 KB
    __shared__ float red[4];

    const int tid = threadIdx.x;
    const int bid = (blockIdx.x & 7) * (NBLOCKS / 8) + (blockIdx.x >> 3); // XCD chunks
    const int b  = bid >> 9;          // 0..15
    const int ts = (bid >> 4) & 31;   // row strip 0..31
    const int tx = bid & 15;          // col strip 0..15

    const float* __restrict__ pb = pred + (size_t)b * (CH * HW);
    const float* __restrict__ gb = gt   + (size_t)b * (CH * HW);

    // ---- Stage 1: 312 tasks = f4 slot f (0..11) x halo row r (0..25) ----
    // Row-major lanes (consecutive lanes -> consecutive rows): LDS writes
    // stride 172 floats == 12 mod 32 -> rotation-3, conflict-free.
    #pragma unroll
    for (int t = 0; t < 2; ++t) {
        const int task = tid + t * 256;
        if (task < SM_R * 12) {
            const int r  = task % SM_R;
            const int f  = task / SM_R;
            const int gy  = (ts << 4) - HALO + r;
            const int gx0 = (tx << 5) - 8 + (f << 2);
            float4 q0 = make_float4(0.f,0.f,0.f,0.f);
            float4 q1 = q0, q2 = q0, q3 = q0;
            if ((unsigned)gy < H) {
                const bool interior = (gx0 >= 0) && (gx0 + 3 < W);
                #pragma unroll
                for (int ch = 0; ch < CH; ++ch) {
                    const float* __restrict__ prow = pb + ch * HW + gy * W;
                    const float* __restrict__ grow = gb + ch * HW + gy * W;
                    float p0,p1,p2,p3, g0,g1,g2,g3;
                    if (interior) {
                        const float4 P = *(const float4*)(prow + gx0);
                        const float4 G = *(const float4*)(grow + gx0);
                        p0=P.x; p1=P.y; p2=P.z; p3=P.w;
                        g0=G.x; g1=G.y; g2=G.z; g3=G.w;
                    } else {
                        p0 = ((unsigned)(gx0+0) < W) ? prow[gx0+0] : 0.f;
                        p1 = ((unsigned)(gx0+1) < W) ? prow[gx0+1] : 0.f;
                        p2 = ((unsigned)(gx0+2) < W) ? prow[gx0+2] : 0.f;
                        p3 = ((unsigned)(gx0+3) < W) ? prow[gx0+3] : 0.f;
                        g0 = ((unsigned)(gx0+0) < W) ? grow[gx0+0] : 0.f;
                        g1 = ((unsigned)(gx0+1) < W) ? grow[gx0+1] : 0.f;
                        g2 = ((unsigned)(gx0+2) < W) ? grow[gx0+2] : 0.f;
                        g3 = ((unsigned)(gx0+3) < W) ? grow[gx0+3] : 0.f;
                    }
                    q0.x += p0; q0.y += g0; q0.z = fmaf(p0,p0,fmaf(g0,g0,q0.z)); q0.w = fmaf(p0,g0,q0.w);
                    q1.x += p1; q1.y += g1; q1.z = fmaf(p1,p1,fmaf(g1,g1,q1.z)); q1.w = fmaf(p1,g1,q1.w);
                    q2.x += p2; q2.y += g2; q2.z = fmaf(p2,p2,fmaf(g2,g2,q2.z)); q2.w = fmaf(p2,g2,q2.w);
                    q3.x += p3; q3.y += g3; q3.z = fmaf(p3,p3,fmaf(g3,g3,q3.z)); q3.w = fmaf(p3,g3,q3.w);
                }
            }
            const int sc0 = (f << 2) - 3;   // halo col of first pixel in the float4
            if ((unsigned)(sc0+0) < SM_C) plane[r][sc0+0] = q0;
            if ((unsigned)(sc0+1) < SM_C) plane[r][sc0+1] = q1;
            if ((unsigned)(sc0+2) < SM_C) plane[r][sc0+2] = q2;
            if ((unsigned)(sc0+3) < SM_C) plane[r][sc0+3] = q3;
        }
    }
    __syncthreads();

    // ---- Stage 2: horizontal 11-tap sliding sums (104 tasks), regs across barrier ----
    float4 hv[8];
    const bool act2 = tid < SM_R * 4;
    int r2 = 0, j0 = 0;
    if (act2) {
        r2 = tid % SM_R;          // consecutive lanes -> consecutive rows
        j0 = (tid / SM_R) << 3;   // output run start: window cols [j0, j0+17]
        float4 v[18];
        #pragma unroll
        for (int k = 0; k < 11; ++k) v[k] = plane[r2][j0 + k];
        float4 w = v[0];
        #pragma unroll
        for (int k = 1; k < 11; ++k) {
            w.x += v[k].x; w.y += v[k].y; w.z += v[k].z; w.w += v[k].w;
        }
        hv[0] = w;
        #pragma unroll
        for (int s = 1; s < 8; ++s) {
            v[10 + s] = plane[r2][j0 + 10 + s];
            w.x += v[10+s].x - v[s-1].x;
            w.y += v[10+s].y - v[s-1].y;
            w.z += v[10+s].z - v[s-1].z;
            w.w += v[10+s].w - v[s-1].w;
            hv[s] = w;
        }
    }
    __syncthreads();
    if (act2) {
        #pragma unroll
        for (int s = 0; s < 8; ++s) plane[r2][j0 + s] = hv[s];  // phase B: [y][x]
    }
    __syncthreads();

    // ---- Stage 3: vertical 11-tap sliding sums + SSIM (2 rows per thread) ----
    const int x  = tid & 31;
    const int yr = tid >> 5;      // output rows 2yr, 2yr+1; window rows [2yr, 2yr+11]
    float4 v3[12];
    #pragma unroll
    for (int k = 0; k < 12; ++k) v3[k] = plane[2 * yr + k][x];
    float sa = v3[0].x, sb = v3[0].y, sc_ = v3[0].z, se = v3[0].w;
    #pragma unroll
    for (int k = 1; k < 11; ++k) {
        sa += v3[k].x; sb += v3[k].y; sc_ += v3[k].z; se += v3[k].w;
    }
    const float inv_n = 1.0f/363.0f, inv_nm1 = 1.0f/362.0f;
    const float c1 = 1e-4f, c2 = 9e-4f;
    float local = 0.f;
    #pragma unroll
    for (int s = 0; s < 2; ++s) {
        if (s > 0) {
            sa  += v3[11].x - v3[0].x;
            sb  += v3[11].y - v3[0].y;
            sc_ += v3[11].z - v3[0].z;
            se  += v3[11].w - v3[0].w;
        }
        const float mu_p = sa * inv_n;
        const float mu_g = sb * inv_n;
        const float varsum = (sc_ - sa * mu_p - sb * mu_g) * inv_nm1;
        const float cov    = (se - sa * mu_g) * inv_n;
        const float num = (2.f * mu_p * mu_g + c1) * (2.f * cov + c2);
        const float den = (mu_p * mu_p + mu_g * mu_g + c1) * (varsum + c2);
        local = fmaf(num, __builtin_amdgcn_rcpf(den + 1e-8f), local);
    }

    // ---- block reduce ----
    #pragma unroll
    for (int off = 32; off > 0; off >>= 1) local += __shfl_down(local, off);
    if ((tid & 63) == 0) red[tid >> 6] = local;
    __syncthreads();
    if (tid == 0) partial[bid] = red[0] + red[1] + red[2] + red[3];
}

__global__ __launch_bounds__(256) void ssim_final_reduce(
    const float* __restrict__ partial, float* __restrict__ out)
{
    __shared__ float red[4];
    const int tid = threadIdx.x;
    float s = 0.f;
    for (int i = tid; i < NBLOCKS; i += 256) s += partial[i];
    #pragma unroll
    for (int off = 32; off > 0; off >>= 1) s += __shfl_down(s, off);
    if ((tid & 63) == 0) red[tid >> 6] = s;
    __syncthreads();
    if (tid == 0) {
        const float total = red[0] + red[1] + red[2] + red[3];
        out[0] = 1.0f - total * (1.0f / (float)(BATCH * H * W));
    }
}

extern "C" void kernel_launch(void* const* d_in, const int* in_sizes, int n_in,
                              void* d_out, int out_size, void* d_ws, size_t ws_size,
                              hipStream_t stream) {
    const float* pred = (const float*)d_in[0];
    const float* gt   = (const float*)d_in[1];
    float* out        = (float*)d_out;
    float* partial    = (float*)d_ws;

    ssim_tile_kernel<<<NBLOCKS, 256, 0, stream>>>(pred, gt, partial);
    ssim_final_reduce<<<1, 256, 0, stream>>>(partial, out);
}